// Round 12
// baseline (375.741 us; speedup 1.0000x reference)
//
#include <hip/hip_runtime.h>
#include <hip/hip_bf16.h>
#include <math.h>

// ---------------------------------------------------------------------------
// VAR quantizer forward. Round 12: round-8 base (Ss reverted); k_scale
// restructured as (B,2,2) x 512thr z-pixel-split, 78KB LDS -> 2 blocks/CU,
// f32 rest buffer with <=2-addend atomicAdd pooling (deterministic), k_nn
// does split3 on the fly. k_nn body otherwise unchanged.
// Output: [f_hat 1048576][loss 1][idx-as-float 87040]
// ---------------------------------------------------------------------------

#define B_  128
#define V_  4096
#define SN_ 10
#define NPIX_ (B_*32*256)   // 1048576

// ws layout (float offsets)
#define WS_FREST   0
#define WS_RF0     1048576
#define WS_RF1     2097152
#define WS_SLOTA   3145728
#define WS_SLOTB   3211264
#define WS_ESQ     3276800
#define WS_TW      3280896
#define WS_TI      3281472
#define WS_LOSSP   3282048
#define WS_EMBH    3287168
#define WS_EMBM    3352704
#define WS_EMBL    3418240
#define WS_WSPL    3483776
// end ~3511424 floats = 13.4 MB

typedef __attribute__((ext_vector_type(8))) short short8_t;
typedef __attribute__((ext_vector_type(4))) float f32x4;
typedef unsigned long long ull;
#define MFMA(a,b,c) __builtin_amdgcn_mfma_f32_16x16x32_bf16((a),(b),(c),0,0,0)

__device__ inline void gl_lds16(const void* g, void* l) {
  __builtin_amdgcn_global_load_lds((const __attribute__((address_space(1))) void*)g,
                                   (__attribute__((address_space(3))) void*)l, 16, 0, 0);
}
__device__ inline void gl_lds4(const void* g, void* l) {
  __builtin_amdgcn_global_load_lds((const __attribute__((address_space(1))) void*)g,
                                   (__attribute__((address_space(3))) void*)l, 4, 0, 0);
}

// split f32 -> 3 truncated bf16 levels (captures ~24 bits)
__device__ inline void split3(float a, ushort* h, ushort* m, ushort* l) {
  unsigned ua = __float_as_uint(a);
  ushort uh = (ushort)(ua >> 16);
  float fh = __uint_as_float((unsigned)uh << 16);
  float r1 = a - fh;
  ushort um = (ushort)(__float_as_uint(r1) >> 16);
  float fm = __uint_as_float((unsigned)um << 16);
  float r2 = r1 - fm;
  ushort ul = (ushort)(__float_as_uint(r2) >> 16);
  *h = uh; *m = um; *l = ul;
}

// DPP lane shifts within 16-lane rows; bound_ctrl=1 -> zero fill (SAME pad)
__device__ inline short8_t s8_from_laneM1(short8_t v) {
  union { short8_t s; unsigned u[4]; } a, r;
  a.s = v;
#pragma unroll
  for (int i = 0; i < 4; ++i)
    r.u[i] = __builtin_amdgcn_update_dpp(0u, a.u[i], 0x111, 0xF, 0xF, true);
  return r.s;
}
__device__ inline short8_t s8_from_laneP1(short8_t v) {
  union { short8_t s; unsigned u[4]; } a, r;
  a.s = v;
#pragma unroll
  for (int i = 0; i < 4; ++i)
    r.u[i] = __builtin_amdgcn_update_dpp(0u, a.u[i], 0x101, 0xF, 0xF, true);
  return r.s;
}

// --------------------------- prep kernels -----------------------------------

__global__ __launch_bounds__(256) void k_prep(const float* __restrict__ emb,
                                              float* __restrict__ esq,
                                              ushort* __restrict__ eh,
                                              ushort* __restrict__ em,
                                              ushort* __restrict__ el,
                                              float* __restrict__ tw,
                                              int* __restrict__ ti,
                                              ull* __restrict__ slotA,
                                              float* __restrict__ rf1) {
  int bx = blockIdx.x, t = threadIdx.x;
  if (bx < 16) {
    int v = bx * 256 + t;
    const float4* e4 = (const float4*)(emb + (size_t)v * 32);
    float s = 0.f;
#pragma unroll
    for (int half = 0; half < 4; ++half) {
      float4 x0 = e4[half * 2], x1 = e4[half * 2 + 1];
      s += x0.x * x0.x + x0.y * x0.y + x0.z * x0.z + x0.w * x0.w;
      s += x1.x * x1.x + x1.y * x1.y + x1.z * x1.z + x1.w * x1.w;
      float xs[8] = {x0.x, x0.y, x0.z, x0.w, x1.x, x1.y, x1.z, x1.w};
      ushort hs[8], ms[8], ls[8];
#pragma unroll
      for (int j = 0; j < 8; ++j) split3(xs[j], &hs[j], &ms[j], &ls[j]);
      uint4 ph, pm, pl;
      ph.x = (unsigned)hs[0] | ((unsigned)hs[1] << 16); ph.y = (unsigned)hs[2] | ((unsigned)hs[3] << 16);
      ph.z = (unsigned)hs[4] | ((unsigned)hs[5] << 16); ph.w = (unsigned)hs[6] | ((unsigned)hs[7] << 16);
      pm.x = (unsigned)ms[0] | ((unsigned)ms[1] << 16); pm.y = (unsigned)ms[2] | ((unsigned)ms[3] << 16);
      pm.z = (unsigned)ms[4] | ((unsigned)ms[5] << 16); pm.w = (unsigned)ms[6] | ((unsigned)ms[7] << 16);
      pl.x = (unsigned)ls[0] | ((unsigned)ls[1] << 16); pl.y = (unsigned)ls[2] | ((unsigned)ls[3] << 16);
      pl.z = (unsigned)ls[4] | ((unsigned)ls[5] << 16); pl.w = (unsigned)ls[6] | ((unsigned)ls[7] << 16);
      ((uint4*)(eh + (size_t)v * 32))[half] = ph;
      ((uint4*)(em + (size_t)v * 32))[half] = pm;
      ((uint4*)(el + (size_t)v * 32))[half] = pl;
    }
    esq[v] = -0.5f * s;
  } else {
    if (t < 128) slotA[t] = 0ULL;                  // si=0 argmax slots
    for (int i = t; i < 16384; i += 256) rf1[i] = 0.f;   // zero rest buf for si=1
    if (t >= 144) return;
    const int pns[9] = {1, 2, 3, 4, 5, 6, 8, 10, 13};
    int si = t / 16, Y = t % 16;
    int pn = pns[si];
    double src = (Y + 0.5) * (double)pn / 16.0 - 0.5;
    double fl = floor(src);
    const double a = -0.75;
#pragma unroll
    for (int k = 0; k < 4; ++k) {
      double x = fabs(src - (fl + (k - 1)));
      double w;
      if (x <= 1.0)      w = (a + 2.0) * x * x * x - (a + 3.0) * x * x + 1.0;
      else if (x < 2.0)  w = a * x * x * x - 5.0 * a * x * x + 8.0 * a * x - 4.0 * a;
      else               w = 0.0;
      int id = (int)fl + (k - 1);
      id = id < 0 ? 0 : (id > pn - 1 ? pn - 1 : id);
      tw[si * 64 + Y * 4 + k] = (float)w;
      ti[si * 64 + Y * 4 + k] = id;
    }
  }
}

__global__ __launch_bounds__(256) void k_prep2(const float* __restrict__ f,
                                               const float* __restrict__ phiW,
                                               float* __restrict__ rf0,
                                               ushort* __restrict__ wspl) {
  int bx = blockIdx.x, t = threadIdx.x;
  if (bx < 16) {
    // phi weight split: wspl[phi][lvl*9+q][o][ci]
    int i = bx * 256 + t;
    int phi = i >> 10, o = (i >> 5) & 31, ci = i & 31;
    const float* src = phiW + (((size_t)phi * 32 + o) * 32 + ci) * 9;
    ushort* dst = wspl + (size_t)phi * 27648;
#pragma unroll
    for (int q = 0; q < 9; ++q) {
      ushort uh, um, ul;
      split3(src[q], &uh, &um, &ul);
      dst[(size_t)(0 * 9 + q) * 1024 + o * 32 + ci] = uh;
      dst[(size_t)(9 + q) * 1024 + o * 32 + ci] = um;
      dst[(size_t)(18 + q) * 1024 + o * 32 + ci] = ul;
    }
  } else {
    // si=0 NN input: area-pool f to 1x1 -> rest f32 [n][c]
    int tid = (bx - 16) * 256 + t;   // 4096
    int c = tid & 31, n = tid >> 5;
    const float* base = f + ((size_t)n * 32 + c) * 256;
    float s = 0.f;
    for (int yy = 0; yy < 16; ++yy)
      for (int xx = 0; xx < 16; ++xx) s += base[yy * 16 + xx];
    rf0[(size_t)n * 32 + c] = s * ((1.0f / 16.0f) * (1.0f / 16.0f));
  }
}

// --------------------------- NN search (round-8 body, f32-rest A-load) ------
template<int R>
__global__ __launch_bounds__(256) void k_nn(const float* __restrict__ rest_f,
                                            const ushort* __restrict__ emb_h,
                                            const ushort* __restrict__ emb_m,
                                            const ushort* __restrict__ emb_l,
                                            const float* __restrict__ esq_g,
                                            ull* __restrict__ slot,
                                            int rows, int S, int cps) {
  __shared__ ushort lb[2][3][2048];
  __shared__ float les[2][64];
  const int t = threadIdx.x;
  const int w = t >> 6;
  const int col = t & 15;
  const int g = (t >> 4) & 3;
  const int sp = blockIdx.y;
  const int rowbase = blockIdx.x * (64 * R);

  auto stage = [&](int bf, int ch) {
    int cb = sp * cps + ch * 64;
    int code = cb + (t >> 2);
    int u = (t & 3) ^ ((code ^ (code >> 2)) & 3);
    size_t off = (size_t)code * 32 + (size_t)u * 8;
    gl_lds16(emb_h + off, &lb[bf][0][w * 512]);
    gl_lds16(emb_m + off, &lb[bf][1][w * 512]);
    gl_lds16(emb_l + off, &lb[bf][2][w * 512]);
    if ((t & 63) < 16) gl_lds4(esq_g + cb + w * 16 + (t & 15), &les[bf][w * 16]);
  };

  stage(0, 0);

  short8_t ah[R], am[R], al[R];
#pragma unroll
  for (int rt = 0; rt < R; ++rt) {
    int n = rowbase + (w * R + rt) * 16 + col;
    if (n >= rows) n = rows - 1;
    const float* rf = rest_f + (size_t)n * 32 + g * 8;
    f32x4 v0 = *(const f32x4*)rf;
    f32x4 v1 = *(const f32x4*)(rf + 4);
    float vs[8] = {v0[0], v0[1], v0[2], v0[3], v1[0], v1[1], v1[2], v1[3]};
    union { ushort u[8]; short8_t s; } H, M, L;
#pragma unroll
    for (int j = 0; j < 8; ++j) split3(vs[j], &H.u[j], &M.u[j], &L.u[j]);
    ah[rt] = H.s; am[rt] = M.s; al[rt] = L.s;
  }

  float best[R][4];
  int bidx[R][4];
#pragma unroll
  for (int rt = 0; rt < R; ++rt)
#pragma unroll
    for (int r = 0; r < 4; ++r) { best[rt][r] = -3.4e38f; bidx[rt][r] = 0x7fffffff; }

  const int NC = cps >> 6;
  int buf = 0;
  for (int ch = 0; ch < NC; ++ch) {
    if (ch + 1 < NC) {
      stage(buf ^ 1, ch + 1);
      asm volatile("s_waitcnt vmcnt(4)" ::: "memory");
    } else {
      asm volatile("s_waitcnt vmcnt(0)" ::: "memory");
    }
    __builtin_amdgcn_s_barrier();

    int cb0 = sp * cps + ch * 64;
#pragma unroll
    for (int s4 = 0; s4 < 4; ++s4) {
      int cl = s4 * 16 + col;
      int slotbase = (cl * 4 + (g ^ ((cl ^ (cl >> 2)) & 3))) * 8;
      short8_t bh  = *(const short8_t*)&lb[buf][0][slotbase];
      short8_t bm  = *(const short8_t*)&lb[buf][1][slotbase];
      short8_t bl2 = *(const short8_t*)&lb[buf][2][slotbase];
      float es = les[buf][cl];
      f32x4 c0 = {es, es, es, es};
      f32x4 acc[R];
      // per-acc order identical to rounds 2-11: hh,hm,mh,hl,mm,lh
#pragma unroll
      for (int rt = 0; rt < R; ++rt) acc[rt] = MFMA(ah[rt], bh, c0);
#pragma unroll
      for (int rt = 0; rt < R; ++rt) acc[rt] = MFMA(ah[rt], bm, acc[rt]);
#pragma unroll
      for (int rt = 0; rt < R; ++rt) acc[rt] = MFMA(am[rt], bh, acc[rt]);
#pragma unroll
      for (int rt = 0; rt < R; ++rt) acc[rt] = MFMA(ah[rt], bl2, acc[rt]);
#pragma unroll
      for (int rt = 0; rt < R; ++rt) acc[rt] = MFMA(am[rt], bm, acc[rt]);
#pragma unroll
      for (int rt = 0; rt < R; ++rt) acc[rt] = MFMA(al[rt], bh, acc[rt]);
      int code = cb0 + cl;
#pragma unroll
      for (int rt = 0; rt < R; ++rt)
#pragma unroll
        for (int r = 0; r < 4; ++r)
          if (acc[rt][r] > best[rt][r]) { best[rt][r] = acc[rt][r]; bidx[rt][r] = code; }
    }
    __syncthreads();
    buf ^= 1;
  }

  // 16-lane reduce then one packed atomicMax per row
#pragma unroll
  for (int rt = 0; rt < R; ++rt)
#pragma unroll
    for (int r = 0; r < 4; ++r) {
      float bd = best[rt][r];
      int bi = bidx[rt][r];
#pragma unroll
      for (int mm2 = 1; mm2 < 16; mm2 <<= 1) {
        float od = __shfl_xor(bd, mm2, 16);
        int oi = __shfl_xor(bi, mm2, 16);
        if (od > bd || (od == bd && oi < bi)) { bd = od; bi = oi; }
      }
      if ((t & 15) == 0) {
        int rown = rowbase + (w * R + rt) * 16 + g * 4 + r;
        if (rown < rows) {
          unsigned mu = __float_as_uint(bd);
          mu ^= (mu & 0x80000000u) ? 0xFFFFFFFFu : 0x80000000u;
          ull key = ((ull)mu << 32) | (unsigned)(~bi);
          atomicMax(&slot[rown], key);
        }
      }
    }
}

// --------------------------- fused per-scale kernel -------------------------
// grid (B, 2 outch-groups, 2 pixel-halves), 512 thr, ~78 KB LDS -> 2 blocks/CU.
// wave w owns output row z*8+w. h_bf holds the 9 halo rows (local).
template<bool LAST>
__global__ __launch_bounds__(512, 4) void k_scale(const ull* __restrict__ slot_in,
                                                  ull* __restrict__ slot_next,
                                                  float* __restrict__ rest_next,
                                                  float* __restrict__ rest_zero,
                                                  const float* __restrict__ emb,
                                                  const float* __restrict__ tw,
                                                  const int* __restrict__ ti,
                                                  const ushort* __restrict__ wspl_k,
                                                  const float* __restrict__ bias,
                                                  const float* __restrict__ f,
                                                  const float* __restrict__ fr_in,
                                                  float* __restrict__ fr_out,
                                                  float* __restrict__ fhat_out,
                                                  float* __restrict__ out_idx_f,
                                                  float* __restrict__ lossp,
                                                  int pn, int si, int pn_next,
                                                  int rows_next, int rows_z2) {
  __shared__ ushort h_bf[3][144][32];      // 27648 B (col-group XOR swz by pix&3)
  __shared__ float xt8[8][208];            // 6656 B
  __shared__ float hsm8[8][176];           // 5632 B
  __shared__ float h_my[16][128];          // 8192 B (aliased as poolb after conv)
  __shared__ ushort w_lds[27][16][36];     // 31104 B (round-8 padded layout)
  __shared__ int ci_s[256];
  __shared__ float redw[8];

  const int b = blockIdx.x;
  const int cog = blockIdx.y * 16;
  const int z = blockIdx.z;
  const int t = threadIdx.x;
  const int pn2 = pn * pn;
  const int w = t >> 6, l = t & 63;
  const int X = l & 15, kq = l >> 4;
  const int grow = z * 8 + w;              // this wave's output row
  const int pix = grow * 16 + X;
  const int rowbase = z ? 7 : 0;           // h_bf local row 0 = global row rowbase

  // ---- phase 0: slots -> codes (+ idx out); fr (+f) prefetch; weights -> LDS
  for (int rem = t; rem < pn2; rem += 512) {
    ull sv = slot_in[b * pn2 + rem];
    int code = (int)(~(unsigned)sv);
    ci_s[rem] = code;
    if (blockIdx.y == 0 && z == 0) out_idx_f[b * pn2 + rem] = (float)code;
  }
  float fr_old[4], f_old[4];
#pragma unroll
  for (int r = 0; r < 4; ++r) {
    size_t ga = ((size_t)b * 32 + cog + kq * 4 + r) * 256 + pix;
    fr_old[r] = fr_in[ga];
    f_old[r] = LAST ? f[ga] : 0.f;
  }
  for (int i = t; i < 1728; i += 512) {
    int seg = i & 3;
    int o = (i >> 2) & 15;
    int lq = i >> 6;
    const ushort* src = wspl_k + ((size_t)lq * 32 + cog + o) * 32 + seg * 8;
    *(short8_t*)&w_lds[lq][o][seg * 8] = *(const short8_t*)src;
  }
  __syncthreads();

  // ---- build h (h_bf bf16x3 for 9 halo rows, h_my f32 for own 8 rows x 16ch)
  if (LAST) {
    const float4* emb4 = (const float4*)emb;
    for (int i = t; i < 1152; i += 512) {       // 144 pix x 8 quads
      int lp = i % 144, cq = i / 144;
      int gp = rowbase * 16 + lp;               // global pixel
      float4 e = emb4[(size_t)ci_s[gp] * 8 + cq];
      float vs[4] = {e.x, e.y, e.z, e.w};
#pragma unroll
      for (int j = 0; j < 4; ++j) {
        int c = cq * 4 + j;
        ushort uh, um, ul; split3(vs[j], &uh, &um, &ul);
        int sc = (c & 7) + (((c >> 3) ^ (lp & 3)) << 3);
        h_bf[0][lp][sc] = uh; h_bf[1][lp][sc] = um; h_bf[2][lp][sc] = ul;
        int grr = rowbase + (lp >> 4);
        int cl = c - cog;
        if ((unsigned)cl < 16u && (grr >> 3) == z)
          h_my[cl][(grr - z * 8) * 16 + (lp & 15)] = vs[j];
      }
    }
    __syncthreads();
  } else {
    const float4* emb4 = (const float4*)emb;
#pragma unroll 1
    for (int P = 0; P < 4; ++P) {               // 8 channels per pass
      // gather hsm8
      for (int i = t; i < pn2 * 2; i += 512) {
        int rem = i >> 1, hf = i & 1;
        float4 e = emb4[(size_t)ci_s[rem] * 8 + P * 2 + hf];
        hsm8[hf * 4 + 0][rem] = e.x;
        hsm8[hf * 4 + 1][rem] = e.y;
        hsm8[hf * 4 + 2][rem] = e.z;
        hsm8[hf * 4 + 3][rem] = e.w;
      }
      __syncthreads();
      // x-interp -> xt8
      int e1n = 8 * pn * 16;
      for (int i = t; i < e1n; i += 512) {
        int Xi = i & 15, r2 = i >> 4;
        int y = r2 % pn, c8 = r2 / pn;
        float a = 0.f;
#pragma unroll
        for (int u = 0; u < 4; ++u)
          a += tw[si * 64 + Xi * 4 + u] * hsm8[c8][y * pn + ti[si * 64 + Xi * 4 + u]];
        xt8[c8][y * 16 + Xi] = a;
      }
      __syncthreads();
      // y-interp for the 9 local rows -> h_bf (+h_my for own rows/chs)
      for (int i = t; i < 1152; i += 512) {     // 144 pix x 8 ch
        int lp = i % 144, c8 = i / 144;
        int Xi = lp & 15, lr = lp >> 4;
        int gY = rowbase + lr;
        float a = 0.f;
#pragma unroll
        for (int u = 0; u < 4; ++u)
          a += tw[si * 64 + gY * 4 + u] * xt8[c8][ti[si * 64 + gY * 4 + u] * 16 + Xi];
        int c = P * 8 + c8;
        ushort uh, um, ul; split3(a, &uh, &um, &ul);
        int sc = (c & 7) + (((c >> 3) ^ (lp & 3)) << 3);
        h_bf[0][lp][sc] = uh; h_bf[1][lp][sc] = um; h_bf[2][lp][sc] = ul;
        int cl = c - cog;
        if ((unsigned)cl < 16u && (gY >> 3) == z)
          h_my[cl][(gY - z * 8) * 16 + Xi] = a;
      }
      __syncthreads();
    }
  }

  // ---- conv via MFMA (wave = output row grow)
  f32x4 accA, accB;
#pragma unroll
  for (int r = 0; r < 4; ++r) {
    accA[r] = bias[cog + kq * 4 + r];
    accB[r] = 0.f;
  }

  for (int dy = 0; dy < 3; ++dy) {
    int gYp = grow + dy - 1;
    bool ok = (gYp >= 0 && gYp < 16);
    short8_t bc[3];
    if (ok) {
      int lp = (gYp - rowbase) * 16 + X;
      int sc = ((kq ^ (lp & 3)) << 3);
#pragma unroll
      for (int lv = 0; lv < 3; ++lv)
        bc[lv] = *(const short8_t*)&h_bf[lv][lp][sc];
    }
#pragma unroll
    for (int dx = 0; dx < 3; ++dx) {
      int q = dy * 3 + dx;
      short8_t aH = *(const short8_t*)&w_lds[0 * 9 + q][l & 15][kq * 8];
      short8_t aM = *(const short8_t*)&w_lds[9 + q][l & 15][kq * 8];
      short8_t aL = *(const short8_t*)&w_lds[18 + q][l & 15][kq * 8];
      if (!ok) continue;
      short8_t bH = bc[0], bM = bc[1], bL = bc[2];
      if (dx == 0) { bH = s8_from_laneM1(bH); bM = s8_from_laneM1(bM); bL = s8_from_laneM1(bL); }
      else if (dx == 2) { bH = s8_from_laneP1(bH); bM = s8_from_laneP1(bM); bL = s8_from_laneP1(bL); }
      accA = MFMA(aH, bH, accA);
      accB = MFMA(aH, bM, accB);
      accA = MFMA(aM, bH, accA);
      accB = MFMA(aH, bL, accB);
      accA = MFMA(aM, bM, accA);
      accB = MFMA(aL, bH, accB);
    }
  }

  // ---- epilogue: residual mix, f_rest RMW, loss
  float nf_r[4];
  float lsum = 0.f;
#pragma unroll
  for (int r = 0; r < 4; ++r) {
    int ol = kq * 4 + r;
    float convv = accA[r] + accB[r];
    float outv = 0.5f * h_my[ol][w * 16 + X] + 0.5f * convv;
    float nf = fr_old[r] - outv;
    size_t ga = ((size_t)b * 32 + cog + ol) * 256 + pix;
    if (LAST) {
      fhat_out[ga] = f_old[r] - nf;
    } else {
      fr_out[ga] = nf;
    }
    nf_r[r] = nf;
    lsum += nf * nf;
  }

  // ---- pool partials (atomicAdd into f32 rest_next; <=2 addends -> det) ----
  if (!LAST) {
    __syncthreads();                           // h_my reads done -> reuse as poolb
    float* poolb = &h_my[0][0];                // [16][128]
#pragma unroll
    for (int r = 0; r < 4; ++r)
      poolb[(kq * 4 + r) * 128 + w * 16 + X] = nf_r[r];
    __syncthreads();
    int pn2n = pn_next * pn_next;
    int z8 = z * 8;
    for (int i = t; i < 16 * pn2n; i += 512) {
      int o = i & 15, rem = i >> 4;
      int y = rem / pn_next, x = rem - y * pn_next;
      int sy = (y * 16) / pn_next, ey = ((y + 1) * 16 + pn_next - 1) / pn_next;
      int sx = (x * 16) / pn_next, ex = ((x + 1) * 16 + pn_next - 1) / pn_next;
      int lsy = sy > z8 ? sy : z8;
      int ley = ey < z8 + 8 ? ey : z8 + 8;
      if (lsy >= ley) continue;
      float s = 0.f;
      for (int yy = lsy; yy < ley; ++yy)
        for (int xx = sx; xx < ex; ++xx) s += poolb[o * 128 + (yy - z8) * 16 + xx];
      float val = s * ((1.0f / (float)(ey - sy)) * (1.0f / (float)(ex - sx)));
      atomicAdd(&rest_next[(size_t)(b * pn2n + rem) * 32 + cog + o], val);
    }
    // zero the consumed rest buffer (for si+2) and next slots, distributed
    int blk = (z * 2 + blockIdx.y) * 128 + b;  // 0..511
    if (rows_z2 > 0) {
      int tot = rows_z2 * 32;
      int stride = (tot + 511) >> 9;
      int base = blk * stride;
      for (int i = t; i < stride; i += 512) {
        int s = base + i;
        if (s < tot) rest_zero[s] = 0.f;
      }
    }
    {
      int stride = (rows_next + 511) >> 9;
      int base = blk * stride;
      for (int i = t; i < stride; i += 512) {
        int s = base + i;
        if (s < rows_next) slot_next[s] = 0ULL;
      }
    }
  }

  // ---- loss partial
#pragma unroll
  for (int off = 32; off > 0; off >>= 1) lsum += __shfl_down(lsum, off);
  if (l == 0) redw[w] = lsum;
  __syncthreads();
  if (t == 0) {
    float s2 = 0.f;
#pragma unroll
    for (int i = 0; i < 8; ++i) s2 += redw[i];
    lossp[si * 512 + (z * 2 + blockIdx.y) * 128 + b] = s2;
  }
}

__global__ __launch_bounds__(256) void k_lossfin(const float* __restrict__ part,
                                                 float* __restrict__ out) {
  int t = threadIdx.x;
  float s = 0.f;
  for (int i = t; i < SN_ * 512; i += 256) s += part[i];
  __shared__ float red[256];
  red[t] = s;
  __syncthreads();
  for (int o = 128; o > 0; o >>= 1) {
    if (t < o) red[t] += red[t + o];
    __syncthreads();
  }
  if (t == 0) out[NPIX_] = red[0] * (1.25f / (10.0f * (float)NPIX_));
}

// --------------------------- host side -------------------------------------

static void compute_phi_k(int* ks) {
  const int K = 4;
  double start = 1.0 / (3.0 * K);
  double stop = 1.0 - 1.0 / (3.0 * K);
  double step = (stop - start) / (K - 1);
  double ticks[4];
  for (int i = 0; i < K; ++i) ticks[i] = (double)i * step + start;
  ticks[K - 1] = stop;
  for (int si = 0; si < SN_; ++si) {
    double x = (double)si / (SN_ - 1);
    int best = 0;
    double bd = fabs(ticks[0] - x);
    for (int i = 1; i < K; ++i) {
      double d = fabs(ticks[i] - x);
      if (d < bd) { bd = d; best = i; }
    }
    ks[si] = best;
  }
}

extern "C" void kernel_launch(void* const* d_in, const int* in_sizes, int n_in,
                              void* d_out, int out_size, void* d_ws, size_t ws_size,
                              hipStream_t stream) {
  (void)in_sizes; (void)n_in; (void)out_size; (void)ws_size;
  const float* f    = (const float*)d_in[0];
  const float* emb  = (const float*)d_in[1];
  const float* phiW = (const float*)d_in[2];
  const float* phiB = (const float*)d_in[3];
  float* out = (float*)d_out;
  float* ws = (float*)d_ws;

  float* f_rest = ws + WS_FREST;
  float* rf0    = ws + WS_RF0;
  float* rf1    = ws + WS_RF1;
  ull*   slotA  = (ull*)(ws + WS_SLOTA);
  ull*   slotB  = (ull*)(ws + WS_SLOTB);
  float* esq    = ws + WS_ESQ;
  float* tw     = ws + WS_TW;
  int*   ti     = (int*)(ws + WS_TI);
  float* lossp  = ws + WS_LOSSP;
  ushort* emb_h  = (ushort*)(ws + WS_EMBH);
  ushort* emb_m  = (ushort*)(ws + WS_EMBM);
  ushort* emb_l  = (ushort*)(ws + WS_EMBL);
  ushort* wspl   = (ushort*)(ws + WS_WSPL);

  static const int pns[SN_] = {1, 2, 3, 4, 5, 6, 8, 10, 13, 16};
  static const int Rs[SN_]  = {1, 1, 1, 2, 2, 2, 4, 4, 4, 4};
  static const int Ss[SN_]  = {64, 64, 32, 32, 16, 16, 16, 16, 8, 4};
  int ks[SN_];
  compute_phi_k(ks);

  k_prep<<<17, 256, 0, stream>>>(emb, esq, emb_h, emb_m, emb_l, tw, ti, slotA, rf1);
  k_prep2<<<32, 256, 0, stream>>>(f, phiW, rf0, wspl);

  int idx_off = 0;
  for (int si = 0; si < SN_; ++si) {
    int pn = pns[si];
    int pn2 = pn * pn;
    int rows = B_ * pn2;
    int R = Rs[si], S = Ss[si];
    int cps = V_ / S;
    int rowblocks = (rows + 64 * R - 1) / (64 * R);
    ull* slot_cur = (si & 1) ? slotB : slotA;
    ull* slot_nxt = (si & 1) ? slotA : slotB;
    float* rest_cur = (si & 1) ? rf1 : rf0;
    float* rest_nxt = (si & 1) ? rf0 : rf1;

    dim3 grid(rowblocks, S);
    if (R == 1)
      k_nn<1><<<grid, 256, 0, stream>>>(rest_cur, emb_h, emb_m, emb_l,
                                        esq, slot_cur, rows, S, cps);
    else if (R == 2)
      k_nn<2><<<grid, 256, 0, stream>>>(rest_cur, emb_h, emb_m, emb_l,
                                        esq, slot_cur, rows, S, cps);
    else
      k_nn<4><<<grid, 256, 0, stream>>>(rest_cur, emb_h, emb_m, emb_l,
                                        esq, slot_cur, rows, S, cps);

    bool last = (si == SN_ - 1);
    int pn_next = last ? 0 : pns[si + 1];
    int rows_next = last ? 0 : B_ * pn_next * pn_next;
    int rows_z2 = (si + 2 <= SN_ - 1) ? B_ * pns[si + 2] * pns[si + 2] : 0;
    const ushort* wsp = wspl + (size_t)ks[si] * 27648;
    const float* bi = phiB + (size_t)ks[si] * 32;
    if (last)
      k_scale<true><<<dim3(B_, 2, 2), 512, 0, stream>>>(
          slot_cur, slot_nxt, rest_nxt, rest_cur, emb, tw, ti, wsp, bi, f,
          f_rest, f_rest, out,
          out + NPIX_ + 1 + idx_off, lossp,
          pn, si, pn_next, rows_next, rows_z2);
    else
      k_scale<false><<<dim3(B_, 2, 2), 512, 0, stream>>>(
          slot_cur, slot_nxt, rest_nxt, rest_cur, emb, tw, ti, wsp, bi, f,
          (si == 0) ? f : f_rest, f_rest, nullptr,
          out + NPIX_ + 1 + idx_off, lossp,
          pn, si, pn_next, rows_next, rows_z2);
    idx_off += rows;
  }

  k_lossfin<<<1, 256, 0, stream>>>(lossp, out);
}